// Round 11
// baseline (62.945 us; speedup 1.0000x reference)
//
#include <hip/hip_runtime.h>

#define BATCH 4096
#define TPTS 512
#define BLK 512   // 8 waves/block -> 2 waves per SIMD (round-robin over 4 SIMDs/CU)
// RK4 @ h = dt (uniform grid, t = arange). Scaled state p=beta*h*S, q=alpha*h*E, I unscaled.
// J-identity: I1+2I2+2I3+I4 = 6*I + (k1+k2+k3). R/M folded into wb.
// Model: solo wave issues 1 instr/4cyc (R2/R8/R9); per-SIMD scheduler can interleave 2 waves
// on alternate cycles (m07 chip-throughput evidence) -> co-locating 2 waves/SIMD ~halves time.
// Body identical to R9 (R10's unroll+setprio regressed; reverted).
//
// Register map (all clobbered):
//   v30:31 CPQ2  v32:33 CPQ4  v34:35 CPQ6  v36:37 TWO
//   v40:41 PQ  v42 I  v43 wb  v73 voff
//   v44..51 nd1..nd4  v52..55 k1..k4  v56 I2  v57 I3  v58 I4
//   v60:65 PQ2..PQ4  v66:67 acc  v68..71 t,sk,u,aI  v72 o

#define CLOB \
    "v30","v31","v32","v33","v34","v35","v36","v37", \
    "v40","v41","v42","v43","v44","v45","v46","v47","v48","v49", \
    "v50","v51","v52","v53","v54","v55","v56","v57","v58", \
    "v60","v61","v62","v63","v64","v65","v66","v67","v68","v69", \
    "v70","v71","v72","v73","memory"

__global__ __launch_bounds__(BLK, 1) void seirm_traj_kernel(
    const float* __restrict__ ze_init,  // [1, B, 5]
    const float* __restrict__ tv,       // [T]
    const float* __restrict__ theta,    // [4] beta, alpha, gamma, mu
    const float* __restrict__ Wv,       // [1, 5]
    const float* __restrict__ bv,       // [1]
    float* __restrict__ out)            // [T, B, 1]
{
    const int b = blockIdx.x * BLK + (int)threadIdx.x;

    const float beta  = theta[0];
    const float alpha = theta[1];
    const float gam   = theta[2];
    const float mu    = theta[3];

    const float w0 = Wv[0], w1 = Wv[1], w2 = Wv[2], w3 = Wv[3], w4 = Wv[4];
    const float bias = bv[0];

    const float h  = tv[1] - tv[0];     // uniform grid
    const float bh = beta * h;
    const float ah = alpha * h;
    const float gh = (gam + mu) * h;
    const float ngh = -gh;              // pre-negated (avoid asm src modifier)
    constexpr float SIXTH = 1.0f / 6.0f;

    const float w0p = w0 / bh;
    const float w1p = w1 / ah;
    const float wJ  = fmaf(w3, gam, w4 * mu);
    const float cJ1 = wJ * h;
    const float cJ2 = wJ * h * SIXTH;

    const float S0 = ze_init[b * 5 + 0];
    const float E0 = ze_init[b * 5 + 1];
    const float I0 = ze_init[b * 5 + 2];
    const float R0 = ze_init[b * 5 + 3];
    const float M0 = ze_init[b * 5 + 4];

    const float p0  = bh * S0;
    const float q0  = ah * E0;
    const float wb0 = fmaf(w3, R0, fmaf(w4, M0, bias));

    // t=0 output
    out[b] = fmaf(w0p, p0, fmaf(w1p, q0, fmaf(w2, I0, wb0)));

    const int voff0 = (b << 2) + BATCH * 4;   // first store -> row 1

    // ---- init fixed registers ----
    asm volatile(
        "v_mov_b32 v40, %0\n\t"
        "v_mov_b32 v41, %1\n\t"
        "v_mov_b32 v42, %2\n\t"
        "v_mov_b32 v43, %3\n\t"
        "v_mov_b32 v73, %4\n\t"
        "v_mov_b32 v30, %5\n\t"
        "v_mov_b32 v31, %6\n\t"
        "v_mov_b32 v32, %7\n\t"
        "v_mov_b32 v33, %8\n\t"
        "v_mov_b32 v34, %9\n\t"
        "v_mov_b32 v35, %10\n\t"
        "v_mov_b32 v36, 2.0\n\t"
        "v_mov_b32 v37, 2.0\n\t"
        :
        : "v"(p0), "v"(q0), "v"(I0), "v"(wb0), "v"(voff0),
          "v"(-0.5f * bh), "v"(0.5f * ah), "v"(-bh), "v"(ah),
          "v"(-bh * SIXTH), "v"(ah * SIXTH)
        : CLOB);

    // ---- 511 RK4 steps, R9 35-slot asm body ----
    for (int i = 1; i < TPTS; ++i) {
        asm volatile(
            // stage 1
            "v_mul_f32 v44, v40, v42\n\t"            // n1 = p*I
            "v_sub_f32 v45, v44, v41\n\t"            // d1 = n1 - q
            "v_fma_f32 v52, %0, v42, v41\n\t"        // k1 = -gh*I + q
            "v_pk_fma_f32 v[60:61], v[30:31], v[44:45], v[40:41]\n\t" // PQ2
            "v_fma_f32 v56, 0.5, v52, v42\n\t"       // I2
            // stage 2
            "v_mul_f32 v46, v60, v56\n\t"
            "v_sub_f32 v47, v46, v61\n\t"
            "v_fma_f32 v53, %0, v56, v61\n\t"
            "v_pk_fma_f32 v[62:63], v[30:31], v[46:47], v[40:41]\n\t" // PQ3
            "v_fma_f32 v57, 0.5, v53, v42\n\t"       // I3
            // stage 3
            "v_mul_f32 v48, v62, v57\n\t"
            "v_sub_f32 v49, v48, v63\n\t"
            "v_fma_f32 v54, %0, v57, v63\n\t"
            "v_pk_fma_f32 v[64:65], v[32:33], v[48:49], v[40:41]\n\t" // PQ4
            "v_add_f32 v58, v54, v42\n\t"            // I4 = k3 + I
            // stage 4
            "v_mul_f32 v50, v64, v58\n\t"
            "v_sub_f32 v51, v50, v65\n\t"
            "v_fma_f32 v55, %0, v58, v65\n\t"
            // PQ combine: acc = nd1 + 2*nd2 + 2*nd3 + nd4 ; PQ += CPQ6*acc
            "v_pk_fma_f32 v[66:67], v[36:37], v[46:47], v[44:45]\n\t"
            "v_pk_fma_f32 v[66:67], v[36:37], v[48:49], v[66:67]\n\t"
            "v_pk_add_f32 v[66:67], v[66:67], v[50:51]\n\t"
            "v_pk_fma_f32 v[40:41], v[34:35], v[66:67], v[40:41]\n\t"
            // I / J(folded wb) combine
            "v_add_f32 v68, v53, v54\n\t"            // t  = k2+k3
            "v_add_f32 v69, v52, v68\n\t"            // sk = k1+t
            "v_add_f32 v70, v69, v68\n\t"            // u  = sk+t
            "v_add_f32 v71, v70, v55\n\t"            // aI = u+k4
            "v_fma_f32 v43, %1, v42, v43\n\t"        // wb += cJ1*I_old
            "v_fma_f32 v43, %2, v69, v43\n\t"        // wb += cJ2*sk
            "v_fma_f32 v42, %3, v71, v42\n\t"        // I  += (1/6)*aI
            // output
            "v_fma_f32 v72, %4, v42, v43\n\t"        // o = w2*I + wb
            "v_fma_f32 v72, %5, v40, v72\n\t"        // o += w0p*p
            "v_fma_f32 v72, %6, v41, v72\n\t"        // o += w1p*q
            "global_store_dword v73, v72, %7\n\t"
            "v_add_u32 v73, 0x4000, v73\n\t"         // voff += BATCH*4
            :
            : "s"(ngh), "s"(cJ1), "s"(cJ2), "s"(SIXTH),
              "s"(w2), "s"(w0p), "s"(w1p), "s"(out)
            : CLOB);
    }
}

extern "C" void kernel_launch(void* const* d_in, const int* in_sizes, int n_in,
                              void* d_out, int out_size, void* d_ws, size_t ws_size,
                              hipStream_t stream) {
    const float* ze = (const float*)d_in[0];
    const float* tv = (const float*)d_in[1];
    const float* th = (const float*)d_in[2];
    const float* Wv = (const float*)d_in[3];
    const float* bv = (const float*)d_in[4];
    float* out = (float*)d_out;

    seirm_traj_kernel<<<BATCH / BLK, BLK, 0, stream>>>(ze, tv, th, Wv, bv, out);
}

// Round 12
// 45.536 us; speedup vs baseline: 1.3823x; 1.3823x over previous
//
#include <hip/hip_runtime.h>

#define BATCH 4096
#define TPTS 512
// RK4 @ h = dt (uniform grid, t = arange). Scaled state p=beta*h*S, q=alpha*h*E, I unscaled.
// Identities: aj = I1+2I2+2I3+I4 = 6I+sk;  Σw·q_j = aI + gh·aj;  Σw·d_j = Σw·n_j − Σw·q_j.
// => q-combine needs only acc_x (n-sum), aI, m=6I+sk: acc_d = acc_x − aI − gh·m. d4, k-pairs gone.
// Machine model (R2/R8/R9/R11): 1 wave/CU best; solo-wave cadence ~4 cyc/instr, ILP-insensitive;
// pk ops = 2 slots (no win over scalar). => minimize wave instruction count: 37 VALU + store.
// Store: persistent SGPR base s[40:41] bumped on the SALU pipe (co-issues); voffset constant.
//
// Persistent regs (clobbered in every asm block): v40 p, v41 q, v42 I, v43 wb, v73 voff(const)
// Temps: v44..47 n1..n4, v48..51 k1..k4, v52 d, v53 p_s, v54 q_s, v55 I_s,
//        v56 acc_x, v57 t/u/aI, v58 sk, v59 m, v60 s1/acc_d, v61 o.  s[40:41] out base.

#define CLOB \
    "v40","v41","v42","v43","v44","v45","v46","v47","v48","v49", \
    "v50","v51","v52","v53","v54","v55","v56","v57","v58","v59", \
    "v60","v61","v73","s40","s41","scc","memory"

__global__ __launch_bounds__(64, 1) void seirm_traj_kernel(
    const float* __restrict__ ze_init,  // [1, B, 5]
    const float* __restrict__ tv,       // [T]
    const float* __restrict__ theta,    // [4] beta, alpha, gamma, mu
    const float* __restrict__ Wv,       // [1, 5]
    const float* __restrict__ bv,       // [1]
    float* __restrict__ out)            // [T, B, 1]
{
    const int b = blockIdx.x * 64 + (int)threadIdx.x;

    const float beta  = theta[0];
    const float alpha = theta[1];
    const float gam   = theta[2];
    const float mu    = theta[3];

    const float w0 = Wv[0], w1 = Wv[1], w2 = Wv[2], w3 = Wv[3], w4 = Wv[4];
    const float bias = bv[0];

    const float h  = tv[1] - tv[0];     // uniform grid
    const float bh = beta * h;
    const float ah = alpha * h;
    const float gh = (gam + mu) * h;
    const float ngh = -gh;              // SGPR constant (also used for acc_d)
    constexpr float SIXTH = 1.0f / 6.0f;

    const float cp2 = -0.5f * bh;       // stage 2/3 p coeff
    const float cq2 =  0.5f * ah;       // stage 2/3 q coeff
    const float cp4 = -bh;              // stage 4 p coeff
    const float cq4 =  ah;              // stage 4 q coeff
    const float cp6 = -bh * SIXTH;      // p combine
    const float cq6 =  ah * SIXTH;      // q combine
    const float SIX =  6.0f;

    const float w0p = w0 / bh;
    const float w1p = w1 / ah;
    const float wJ  = fmaf(w3, gam, w4 * mu);
    const float cJm = wJ * h * SIXTH;   // wb += cJm * (6I+sk)

    const float S0 = ze_init[b * 5 + 0];
    const float E0 = ze_init[b * 5 + 1];
    const float I0 = ze_init[b * 5 + 2];
    const float R0 = ze_init[b * 5 + 3];
    const float M0 = ze_init[b * 5 + 4];

    const float p0  = bh * S0;
    const float q0  = ah * E0;
    const float wb0 = fmaf(w3, R0, fmaf(w4, M0, bias));

    // t=0 output
    out[b] = fmaf(w0p, p0, fmaf(w1p, q0, fmaf(w2, I0, wb0)));

    const int voff0 = (b << 2) + BATCH * 4;   // constant: row offset handled by SGPR base bump

    // ---- init persistent registers ----
    asm volatile(
        "s_mov_b64 s[40:41], %5\n\t"
        "v_mov_b32 v40, %0\n\t"
        "v_mov_b32 v41, %1\n\t"
        "v_mov_b32 v42, %2\n\t"
        "v_mov_b32 v43, %3\n\t"
        "v_mov_b32 v73, %4\n\t"
        :
        : "v"(p0), "v"(q0), "v"(I0), "v"(wb0), "v"(voff0), "s"(out)
        : CLOB);

    // ---- 511 RK4 steps, 37-VALU body ----
    for (int i = 1; i < TPTS; ++i) {
        asm volatile(
            // stage 1
            "v_mul_f32 v44, v40, v42\n\t"         // n1 = p*I
            "v_fma_f32 v48, %0, v42, v41\n\t"     // k1 = -gh*I + q
            "v_sub_f32 v52, v44, v41\n\t"         // d1 = n1 - q
            "v_fma_f32 v53, %1, v44, v40\n\t"     // p2 = cp2*n1 + p
            "v_fma_f32 v54, %2, v52, v41\n\t"     // q2 = cq2*d1 + q
            "v_fma_f32 v55, 0.5, v48, v42\n\t"    // I2 = I + k1/2
            // stage 2
            "v_mul_f32 v45, v53, v55\n\t"         // n2
            "v_fma_f32 v49, %0, v55, v54\n\t"     // k2
            "v_sub_f32 v52, v45, v54\n\t"         // d2
            "v_fma_f32 v53, %1, v45, v40\n\t"     // p3
            "v_fma_f32 v54, %2, v52, v41\n\t"     // q3
            "v_fma_f32 v55, 0.5, v49, v42\n\t"    // I3
            // stage 3
            "v_mul_f32 v46, v53, v55\n\t"         // n3
            "v_fma_f32 v50, %0, v55, v54\n\t"     // k3
            "v_sub_f32 v52, v46, v54\n\t"         // d3
            "v_fma_f32 v53, %3, v46, v40\n\t"     // p4 = cp4*n3 + p
            "v_fma_f32 v54, %4, v52, v41\n\t"     // q4 = cq4*d3 + q
            "v_add_f32 v55, v50, v42\n\t"         // I4 = I + k3
            // stage 4 (no d4 needed)
            "v_mul_f32 v47, v53, v55\n\t"         // n4
            "v_fma_f32 v51, %0, v55, v54\n\t"     // k4
            // combine
            "v_fma_f32 v56, 2.0, v45, v44\n\t"    // acc_x = n1 + 2n2
            "v_fma_f32 v56, 2.0, v46, v56\n\t"    //        + 2n3
            "v_add_f32 v56, v56, v47\n\t"         //        + n4
            "v_add_f32 v57, v49, v50\n\t"         // t  = k2+k3
            "v_add_f32 v58, v48, v57\n\t"         // sk = k1+t
            "v_add_f32 v57, v58, v57\n\t"         // u  = sk+t
            "v_add_f32 v57, v57, v51\n\t"         // aI = u+k4
            "v_fma_f32 v59, %8, v42, v58\n\t"     // m = 6*I_old + sk
            "v_fma_f32 v43, %7, v59, v43\n\t"     // wb += cJm*m
            "v_sub_f32 v60, v56, v57\n\t"         // s1 = acc_x - aI
            "v_fma_f32 v60, %0, v59, v60\n\t"     // acc_d = s1 - gh*m
            "v_fma_f32 v40, %5, v56, v40\n\t"     // p += cp6*acc_x
            "v_fma_f32 v41, %6, v60, v41\n\t"     // q += cq6*acc_d
            "v_fma_f32 v42, %9, v57, v42\n\t"     // I += aI/6
            // output
            "v_fma_f32 v61, %10, v42, v43\n\t"    // o = w2*I + wb
            "v_fma_f32 v61, %11, v40, v61\n\t"    // o += w0p*p
            "v_fma_f32 v61, %12, v41, v61\n\t"    // o += w1p*q
            "global_store_dword v73, v61, s[40:41]\n\t"
            "s_add_u32 s40, s40, 0x4000\n\t"      // base += BATCH*4 (scalar pipe)
            "s_addc_u32 s41, s41, 0\n\t"
            :
            : "s"(ngh), "s"(cp2), "s"(cq2), "s"(cp4), "s"(cq4),
              "s"(cp6), "s"(cq6), "s"(cJm), "s"(SIX), "s"(SIXTH),
              "s"(w2), "s"(w0p), "s"(w1p)
            : CLOB);
    }
}

extern "C" void kernel_launch(void* const* d_in, const int* in_sizes, int n_in,
                              void* d_out, int out_size, void* d_ws, size_t ws_size,
                              hipStream_t stream) {
    const float* ze = (const float*)d_in[0];
    const float* tv = (const float*)d_in[1];
    const float* th = (const float*)d_in[2];
    const float* Wv = (const float*)d_in[3];
    const float* bv = (const float*)d_in[4];
    float* out = (float*)d_out;

    seirm_traj_kernel<<<BATCH / 64, 64, 0, stream>>>(ze, tv, th, Wv, bv, out);
}

// Round 13
// 44.001 us; speedup vs baseline: 1.4305x; 1.0349x over previous
//
#include <hip/hip_runtime.h>

#define BATCH 4096
#define TPTS 512
// RK4 @ h = dt (uniform grid, t = arange). Scaled state p=beta*h*S, q=alpha*h*E, I unscaled.
// R12 identities (d4 dropped, acc_d = acc_x - aI - gh*m, m = 6I+sk, wb += cJm*m).
// Machine model (R9/R11/R12 fits): SIMD issues ~1 instr/4cyc for 1-2 resident waves,
// pk_*_f32 = 2 FLOPs in ONE slot. => pack 2 ODEs per thread into pk halves:
// 37 pk per step processes TWO ODEs; adjacent outputs -> one global_store_dwordx2.
// Subs recast as fma with CM1=(-1,-1) pair (no VOP3P modifiers). 7-step unroll (511=73*7).
//
// Pairs: v[40:41] P  v[42:43] Q  v[44:45] I  v[46:47] WB
//   v[48:55] n1..n4  v[56:63] k1..k4  v[64:65] d/s1  v[66:71] Ps,Qs,Is
//   v[72:73] ax  v[74:75] tt/u/aI  v[76:77] sk  v[78:79] m  v[80:81] o   v82 voff
// Consts: v[84:85] NGH  v[86:87] CP2  v[88:89] CQ2  v[90:91] CP4  v[92:93] CQ4
//   v[94:95] CP6  v[96:97] CQ6  v[98:99] CJM  v[100:101] SIX  v[102:103] C6TH
//   v[104:105] CW2  v[106:107] CW0P  v[108:109] CW1P  v[110:111] CM1
//   v[112:113] CHALF  v[114:115] CTWO

#define CLOB \
    "v40","v41","v42","v43","v44","v45","v46","v47","v48","v49", \
    "v50","v51","v52","v53","v54","v55","v56","v57","v58","v59", \
    "v60","v61","v62","v63","v64","v65","v66","v67","v68","v69", \
    "v70","v71","v72","v73","v74","v75","v76","v77","v78","v79", \
    "v80","v81","v82","v84","v85","v86","v87","v88","v89", \
    "v90","v91","v92","v93","v94","v95","v96","v97","v98","v99", \
    "v100","v101","v102","v103","v104","v105","v106","v107","v108","v109", \
    "v110","v111","v112","v113","v114","v115","memory"

#define BODY \
    /* stage 1 */ \
    "v_pk_mul_f32 v[48:49], v[40:41], v[44:45]\n\t"            /* n1 = P*I        */ \
    "v_pk_fma_f32 v[56:57], v[84:85], v[44:45], v[42:43]\n\t"  /* k1 = NGH*I+Q    */ \
    "v_pk_fma_f32 v[64:65], v[110:111], v[42:43], v[48:49]\n\t"/* d  = n1-Q       */ \
    "v_pk_fma_f32 v[66:67], v[86:87], v[48:49], v[40:41]\n\t"  /* Ps = CP2*n1+P   */ \
    "v_pk_fma_f32 v[68:69], v[88:89], v[64:65], v[42:43]\n\t"  /* Qs = CQ2*d+Q    */ \
    "v_pk_fma_f32 v[70:71], v[112:113], v[56:57], v[44:45]\n\t"/* Is = .5*k1+I    */ \
    /* stage 2 */ \
    "v_pk_mul_f32 v[50:51], v[66:67], v[70:71]\n\t"            /* n2              */ \
    "v_pk_fma_f32 v[58:59], v[84:85], v[70:71], v[68:69]\n\t"  /* k2              */ \
    "v_pk_fma_f32 v[64:65], v[110:111], v[68:69], v[50:51]\n\t"/* d = n2-Qs       */ \
    "v_pk_fma_f32 v[66:67], v[86:87], v[50:51], v[40:41]\n\t"  /* Ps              */ \
    "v_pk_fma_f32 v[68:69], v[88:89], v[64:65], v[42:43]\n\t"  /* Qs              */ \
    "v_pk_fma_f32 v[70:71], v[112:113], v[58:59], v[44:45]\n\t"/* Is              */ \
    /* stage 3 */ \
    "v_pk_mul_f32 v[52:53], v[66:67], v[70:71]\n\t"            /* n3              */ \
    "v_pk_fma_f32 v[60:61], v[84:85], v[70:71], v[68:69]\n\t"  /* k3              */ \
    "v_pk_fma_f32 v[64:65], v[110:111], v[68:69], v[52:53]\n\t"/* d = n3-Qs       */ \
    "v_pk_fma_f32 v[66:67], v[90:91], v[52:53], v[40:41]\n\t"  /* Ps = CP4*n3+P   */ \
    "v_pk_fma_f32 v[68:69], v[92:93], v[64:65], v[42:43]\n\t"  /* Qs = CQ4*d+Q    */ \
    "v_pk_add_f32 v[70:71], v[60:61], v[44:45]\n\t"            /* Is = k3+I       */ \
    /* stage 4 */ \
    "v_pk_mul_f32 v[54:55], v[66:67], v[70:71]\n\t"            /* n4              */ \
    "v_pk_fma_f32 v[62:63], v[84:85], v[70:71], v[68:69]\n\t"  /* k4              */ \
    /* combine */ \
    "v_pk_fma_f32 v[72:73], v[114:115], v[50:51], v[48:49]\n\t"/* ax = 2n2+n1     */ \
    "v_pk_fma_f32 v[72:73], v[114:115], v[52:53], v[72:73]\n\t"/* ax += 2n3       */ \
    "v_pk_add_f32 v[72:73], v[72:73], v[54:55]\n\t"            /* ax += n4        */ \
    "v_pk_add_f32 v[74:75], v[58:59], v[60:61]\n\t"            /* tt = k2+k3      */ \
    "v_pk_add_f32 v[76:77], v[56:57], v[74:75]\n\t"            /* sk = k1+tt      */ \
    "v_pk_add_f32 v[74:75], v[76:77], v[74:75]\n\t"            /* u  = sk+tt      */ \
    "v_pk_add_f32 v[74:75], v[74:75], v[62:63]\n\t"            /* aI = u+k4       */ \
    "v_pk_fma_f32 v[78:79], v[100:101], v[44:45], v[76:77]\n\t"/* m = 6I+sk       */ \
    "v_pk_fma_f32 v[46:47], v[98:99], v[78:79], v[46:47]\n\t"  /* WB += CJM*m     */ \
    "v_pk_fma_f32 v[64:65], v[110:111], v[74:75], v[72:73]\n\t"/* s1 = ax-aI      */ \
    "v_pk_fma_f32 v[64:65], v[84:85], v[78:79], v[64:65]\n\t"  /* accd = NGH*m+s1 */ \
    "v_pk_fma_f32 v[40:41], v[94:95], v[72:73], v[40:41]\n\t"  /* P += CP6*ax     */ \
    "v_pk_fma_f32 v[42:43], v[96:97], v[64:65], v[42:43]\n\t"  /* Q += CQ6*accd   */ \
    "v_pk_fma_f32 v[44:45], v[102:103], v[74:75], v[44:45]\n\t"/* I += aI/6       */ \
    /* output */ \
    "v_pk_fma_f32 v[80:81], v[104:105], v[44:45], v[46:47]\n\t"/* o = W2*I+WB     */ \
    "v_pk_fma_f32 v[80:81], v[106:107], v[40:41], v[80:81]\n\t"/* o += W0P*P      */ \
    "v_pk_fma_f32 v[80:81], v[108:109], v[42:43], v[80:81]\n\t"/* o += W1P*Q      */ \
    "global_store_dwordx2 v82, v[80:81], %0\n\t" \
    "v_add_u32 v82, 0x4000, v82\n\t"

__global__ __launch_bounds__(64, 1) void seirm_traj_kernel(
    const float* __restrict__ ze_init,  // [1, B, 5]
    const float* __restrict__ tv,       // [T]
    const float* __restrict__ theta,    // [4] beta, alpha, gamma, mu
    const float* __restrict__ Wv,       // [1, 5]
    const float* __restrict__ bv,       // [1]
    float* __restrict__ out)            // [T, B, 1]
{
    const int b = blockIdx.x * 64 + (int)threadIdx.x;   // pair id: handles batch 2b, 2b+1

    const float beta  = theta[0];
    const float alpha = theta[1];
    const float gam   = theta[2];
    const float mu    = theta[3];

    const float w0 = Wv[0], w1 = Wv[1], w2 = Wv[2], w3 = Wv[3], w4 = Wv[4];
    const float bias = bv[0];

    const float h  = tv[1] - tv[0];     // uniform grid
    const float bh = beta * h;
    const float ah = alpha * h;
    const float gh = (gam + mu) * h;
    const float ngh = -gh;
    constexpr float SIXTH = 1.0f / 6.0f;

    const float cp2 = -0.5f * bh;
    const float cq2 =  0.5f * ah;
    const float cp4 = -bh;
    const float cq4 =  ah;
    const float cp6 = -bh * SIXTH;
    const float cq6 =  ah * SIXTH;

    const float w0p = w0 / bh;
    const float w1p = w1 / ah;
    const float wJ  = fmaf(w3, gam, w4 * mu);
    const float cJm = wJ * h * SIXTH;

    // ---- load both ODE states (batch 2b, 2b+1) ----
    const float SA = ze_init[b * 10 + 0], EA = ze_init[b * 10 + 1];
    const float IA = ze_init[b * 10 + 2];
    const float RA = ze_init[b * 10 + 3], MA = ze_init[b * 10 + 4];
    const float SB = ze_init[b * 10 + 5], EB = ze_init[b * 10 + 6];
    const float IB = ze_init[b * 10 + 7];
    const float RB = ze_init[b * 10 + 8], MB = ze_init[b * 10 + 9];

    const float pA = bh * SA, qA = ah * EA;
    const float pB = bh * SB, qB = ah * EB;
    const float wbA = fmaf(w3, RA, fmaf(w4, MA, bias));
    const float wbB = fmaf(w3, RB, fmaf(w4, MB, bias));

    // t=0 outputs (adjacent pair)
    const float oA0 = fmaf(w0p, pA, fmaf(w1p, qA, fmaf(w2, IA, wbA)));
    const float oB0 = fmaf(w0p, pB, fmaf(w1p, qB, fmaf(w2, IB, wbB)));
    out[2 * b]     = oA0;
    out[2 * b + 1] = oB0;

    const int voff0 = (b << 3) + BATCH * 4;   // byte offset of out[4096 + 2b]

    // ---- init persistent registers (state + voff + 16 const pairs) ----
    asm volatile(
        "v_mov_b32 v40, %0\n\t"  "v_mov_b32 v41, %1\n\t"   // P
        "v_mov_b32 v42, %2\n\t"  "v_mov_b32 v43, %3\n\t"   // Q
        "v_mov_b32 v44, %4\n\t"  "v_mov_b32 v45, %5\n\t"   // I
        "v_mov_b32 v46, %6\n\t"  "v_mov_b32 v47, %7\n\t"   // WB
        "v_mov_b32 v82, %8\n\t"                            // voff
        "v_mov_b32 v84, %9\n\t"   "v_mov_b32 v85, %9\n\t"  // NGH
        "v_mov_b32 v86, %10\n\t"  "v_mov_b32 v87, %10\n\t" // CP2
        "v_mov_b32 v88, %11\n\t"  "v_mov_b32 v89, %11\n\t" // CQ2
        "v_mov_b32 v90, %12\n\t"  "v_mov_b32 v91, %12\n\t" // CP4
        "v_mov_b32 v92, %13\n\t"  "v_mov_b32 v93, %13\n\t" // CQ4
        "v_mov_b32 v94, %14\n\t"  "v_mov_b32 v95, %14\n\t" // CP6
        "v_mov_b32 v96, %15\n\t"  "v_mov_b32 v97, %15\n\t" // CQ6
        "v_mov_b32 v98, %16\n\t"  "v_mov_b32 v99, %16\n\t" // CJM
        "v_mov_b32 v100, %17\n\t" "v_mov_b32 v101, %17\n\t"// SIX
        "v_mov_b32 v102, %18\n\t" "v_mov_b32 v103, %18\n\t"// C6TH
        "v_mov_b32 v104, %19\n\t" "v_mov_b32 v105, %19\n\t"// CW2
        "v_mov_b32 v106, %20\n\t" "v_mov_b32 v107, %20\n\t"// CW0P
        "v_mov_b32 v108, %21\n\t" "v_mov_b32 v109, %21\n\t"// CW1P
        "v_mov_b32 v110, -1.0\n\t" "v_mov_b32 v111, -1.0\n\t" // CM1
        "v_mov_b32 v112, 0.5\n\t"  "v_mov_b32 v113, 0.5\n\t"  // CHALF
        "v_mov_b32 v114, 2.0\n\t"  "v_mov_b32 v115, 2.0\n\t"  // CTWO
        :
        : "v"(pA), "v"(pB), "v"(qA), "v"(qB), "v"(IA), "v"(IB),
          "v"(wbA), "v"(wbB), "v"(voff0),
          "v"(ngh), "v"(cp2), "v"(cq2), "v"(cp4), "v"(cq4),
          "v"(cp6), "v"(cq6), "v"(cJm), "v"(6.0f), "v"(SIXTH),
          "v"(w2), "v"(w0p), "v"(w1p)
        : CLOB);

    // ---- 511 = 73 x 7 RK4 steps, 39-instr pk body each ----
    #pragma clang loop unroll(disable)
    for (int i = 0; i < 73; ++i) {
        asm volatile(
            BODY BODY BODY BODY BODY BODY BODY
            :
            : "s"(out)
            : CLOB);
    }
}

extern "C" void kernel_launch(void* const* d_in, const int* in_sizes, int n_in,
                              void* d_out, int out_size, void* d_ws, size_t ws_size,
                              hipStream_t stream) {
    const float* ze = (const float*)d_in[0];
    const float* tv = (const float*)d_in[1];
    const float* th = (const float*)d_in[2];
    const float* Wv = (const float*)d_in[3];
    const float* bv = (const float*)d_in[4];
    float* out = (float*)d_out;

    // 2048 threads: each integrates 2 ODEs in pk halves
    seirm_traj_kernel<<<(BATCH / 2) / 64, 64, 0, stream>>>(ze, tv, th, Wv, bv, out);
}

// Round 14
// 41.446 us; speedup vs baseline: 1.5187x; 1.0617x over previous
//
#include <hip/hip_runtime.h>

#define BATCH 4096
#define TPTS 512
// RK4 @ h = dt (uniform grid, t = arange). Scaled state p=beta*h*S, q=alpha*h*E, I unscaled.
// J-identity: I1+2I2+2I3+I4 = 6*I + (k1+k2+k3). R/M folded into wb.
// Machine model (R2/R8/R9/R10/R11/R12/R13): solo wave, ~4.8-5 cyc/instr issue cadence,
// invariant to ILP / wave-pairing / pk-vs-scalar / unroll. 1 wave/CU optimal. Wall time =
// 511 x instr_count x cadence. => R9 body (best: 185 cyc/step) minus the v_add voffset bump,
// which moves to the SALU pipe (s[40:41] base bump, validated in R12).
//
// Register map (all clobbered):
//   v30:31 CPQ2  v32:33 CPQ4  v34:35 CPQ6  v36:37 TWO
//   v40:41 PQ  v42 I  v43 wb  v73 voff(const)
//   v44..51 nd1..nd4  v52..55 k1..k4  v56 I2  v57 I3  v58 I4
//   v60:65 PQ2..PQ4  v66:67 acc  v68..71 t,sk,u,aI  v72 o
//   s[40:41] out base (bumped 0x4000/step on SALU)

#define CLOB \
    "v30","v31","v32","v33","v34","v35","v36","v37", \
    "v40","v41","v42","v43","v44","v45","v46","v47","v48","v49", \
    "v50","v51","v52","v53","v54","v55","v56","v57","v58", \
    "v60","v61","v62","v63","v64","v65","v66","v67","v68","v69", \
    "v70","v71","v72","v73","s40","s41","scc","memory"

__global__ __launch_bounds__(64, 1) void seirm_traj_kernel(
    const float* __restrict__ ze_init,  // [1, B, 5]
    const float* __restrict__ tv,       // [T]
    const float* __restrict__ theta,    // [4] beta, alpha, gamma, mu
    const float* __restrict__ Wv,       // [1, 5]
    const float* __restrict__ bv,       // [1]
    float* __restrict__ out)            // [T, B, 1]
{
    const int b = blockIdx.x * 64 + (int)threadIdx.x;

    const float beta  = theta[0];
    const float alpha = theta[1];
    const float gam   = theta[2];
    const float mu    = theta[3];

    const float w0 = Wv[0], w1 = Wv[1], w2 = Wv[2], w3 = Wv[3], w4 = Wv[4];
    const float bias = bv[0];

    const float h  = tv[1] - tv[0];     // uniform grid
    const float bh = beta * h;
    const float ah = alpha * h;
    const float gh = (gam + mu) * h;
    const float ngh = -gh;              // pre-negated (avoid asm src modifier)
    constexpr float SIXTH = 1.0f / 6.0f;

    const float w0p = w0 / bh;
    const float w1p = w1 / ah;
    const float wJ  = fmaf(w3, gam, w4 * mu);
    const float cJ1 = wJ * h;
    const float cJ2 = wJ * h * SIXTH;

    const float S0 = ze_init[b * 5 + 0];
    const float E0 = ze_init[b * 5 + 1];
    const float I0 = ze_init[b * 5 + 2];
    const float R0 = ze_init[b * 5 + 3];
    const float M0 = ze_init[b * 5 + 4];

    const float p0  = bh * S0;
    const float q0  = ah * E0;
    const float wb0 = fmaf(w3, R0, fmaf(w4, M0, bias));

    // t=0 output
    out[b] = fmaf(w0p, p0, fmaf(w1p, q0, fmaf(w2, I0, wb0)));

    const int voff0 = (b << 2) + BATCH * 4;   // constant lane offset; row walked by SGPR base

    // ---- init persistent registers ----
    asm volatile(
        "s_mov_b64 s[40:41], %11\n\t"
        "v_mov_b32 v40, %0\n\t"
        "v_mov_b32 v41, %1\n\t"
        "v_mov_b32 v42, %2\n\t"
        "v_mov_b32 v43, %3\n\t"
        "v_mov_b32 v73, %4\n\t"
        "v_mov_b32 v30, %5\n\t"
        "v_mov_b32 v31, %6\n\t"
        "v_mov_b32 v32, %7\n\t"
        "v_mov_b32 v33, %8\n\t"
        "v_mov_b32 v34, %9\n\t"
        "v_mov_b32 v35, %10\n\t"
        "v_mov_b32 v36, 2.0\n\t"
        "v_mov_b32 v37, 2.0\n\t"
        :
        : "v"(p0), "v"(q0), "v"(I0), "v"(wb0), "v"(voff0),
          "v"(-0.5f * bh), "v"(0.5f * ah), "v"(-bh), "v"(ah),
          "v"(-bh * SIXTH), "v"(ah * SIXTH), "s"(out)
        : CLOB);

    // ---- 511 RK4 steps, R9 body with SALU address bump (one fewer VALU/step) ----
    for (int i = 1; i < TPTS; ++i) {
        asm volatile(
            // stage 1
            "v_mul_f32 v44, v40, v42\n\t"            // n1 = p*I
            "v_sub_f32 v45, v44, v41\n\t"            // d1 = n1 - q
            "v_fma_f32 v52, %0, v42, v41\n\t"        // k1 = -gh*I + q
            "v_pk_fma_f32 v[60:61], v[30:31], v[44:45], v[40:41]\n\t" // PQ2
            "v_fma_f32 v56, 0.5, v52, v42\n\t"       // I2
            // stage 2
            "v_mul_f32 v46, v60, v56\n\t"
            "v_sub_f32 v47, v46, v61\n\t"
            "v_fma_f32 v53, %0, v56, v61\n\t"
            "v_pk_fma_f32 v[62:63], v[30:31], v[46:47], v[40:41]\n\t" // PQ3
            "v_fma_f32 v57, 0.5, v53, v42\n\t"       // I3
            // stage 3
            "v_mul_f32 v48, v62, v57\n\t"
            "v_sub_f32 v49, v48, v63\n\t"
            "v_fma_f32 v54, %0, v57, v63\n\t"
            "v_pk_fma_f32 v[64:65], v[32:33], v[48:49], v[40:41]\n\t" // PQ4
            "v_add_f32 v58, v54, v42\n\t"            // I4 = k3 + I
            // stage 4
            "v_mul_f32 v50, v64, v58\n\t"
            "v_sub_f32 v51, v50, v65\n\t"
            "v_fma_f32 v55, %0, v58, v65\n\t"
            // PQ combine: acc = nd1 + 2*nd2 + 2*nd3 + nd4 ; PQ += CPQ6*acc
            "v_pk_fma_f32 v[66:67], v[36:37], v[46:47], v[44:45]\n\t"
            "v_pk_fma_f32 v[66:67], v[36:37], v[48:49], v[66:67]\n\t"
            "v_pk_add_f32 v[66:67], v[66:67], v[50:51]\n\t"
            "v_pk_fma_f32 v[40:41], v[34:35], v[66:67], v[40:41]\n\t"
            // I / J(folded wb) combine
            "v_add_f32 v68, v53, v54\n\t"            // t  = k2+k3
            "v_add_f32 v69, v52, v68\n\t"            // sk = k1+t
            "v_add_f32 v70, v69, v68\n\t"            // u  = sk+t
            "v_add_f32 v71, v70, v55\n\t"            // aI = u+k4
            "v_fma_f32 v43, %1, v42, v43\n\t"        // wb += cJ1*I_old
            "v_fma_f32 v43, %2, v69, v43\n\t"        // wb += cJ2*sk
            "v_fma_f32 v42, %3, v71, v42\n\t"        // I  += (1/6)*aI
            // output
            "v_fma_f32 v72, %4, v42, v43\n\t"        // o = w2*I + wb
            "v_fma_f32 v72, %5, v40, v72\n\t"        // o += w0p*p
            "v_fma_f32 v72, %6, v41, v72\n\t"        // o += w1p*q
            "global_store_dword v73, v72, s[40:41]\n\t"
            "s_add_u32 s40, s40, 0x4000\n\t"         // row walk on scalar pipe (co-issues)
            "s_addc_u32 s41, s41, 0\n\t"
            :
            : "s"(ngh), "s"(cJ1), "s"(cJ2), "s"(SIXTH),
              "s"(w2), "s"(w0p), "s"(w1p)
            : CLOB);
    }
}

extern "C" void kernel_launch(void* const* d_in, const int* in_sizes, int n_in,
                              void* d_out, int out_size, void* d_ws, size_t ws_size,
                              hipStream_t stream) {
    const float* ze = (const float*)d_in[0];
    const float* tv = (const float*)d_in[1];
    const float* th = (const float*)d_in[2];
    const float* Wv = (const float*)d_in[3];
    const float* bv = (const float*)d_in[4];
    float* out = (float*)d_out;

    seirm_traj_kernel<<<BATCH / 64, 64, 0, stream>>>(ze, tv, th, Wv, bv, out);
}

// Round 15
// 39.875 us; speedup vs baseline: 1.5786x; 1.0394x over previous
//
#include <hip/hip_runtime.h>

#define BATCH 4096
#define TPTS 512
// RK4 @ h = dt (uniform grid, t = arange). Scaled state p=beta*h*S, q=alpha*h*E, I unscaled.
// J-identity: I1+2I2+2I3+I4 = 6*I + (k1+k2+k3). R/M folded into wb.
// Machine law (R9/R12/R13/R14 fits): solo wave => EVERY instruction (VALU/SALU/store) costs
// ~5.0 cyc; no co-issue, no pipe overlap; ILP/occupancy/pk-packing all dead ends (R2/R8/R11/R13).
// Objective = instruction count. R9 body (34 instr) + 7x unroll amortizes ~3 loop-control
// instrs to ~0.4/step: 37 -> 34.4 instr/step.
//
// Register map (all clobbered):
//   v30:31 CPQ2  v32:33 CPQ4  v34:35 CPQ6  v36:37 TWO
//   v40:41 PQ  v42 I  v43 wb  v73 voff
//   v44..51 nd1..nd4  v52..55 k1..k4  v56 I2  v57 I3  v58 I4
//   v60:65 PQ2..PQ4  v66:67 acc  v68..71 t,sk,u,aI  v72 o

#define CLOB \
    "v30","v31","v32","v33","v34","v35","v36","v37", \
    "v40","v41","v42","v43","v44","v45","v46","v47","v48","v49", \
    "v50","v51","v52","v53","v54","v55","v56","v57","v58", \
    "v60","v61","v62","v63","v64","v65","v66","v67","v68","v69", \
    "v70","v71","v72","v73","memory"

#define BODY \
    /* stage 1 */ \
    "v_mul_f32 v44, v40, v42\n\t"            /* n1 = p*I       */ \
    "v_sub_f32 v45, v44, v41\n\t"            /* d1 = n1 - q    */ \
    "v_fma_f32 v52, %0, v42, v41\n\t"        /* k1 = -gh*I + q */ \
    "v_pk_fma_f32 v[60:61], v[30:31], v[44:45], v[40:41]\n\t" \
    "v_fma_f32 v56, 0.5, v52, v42\n\t"       /* I2             */ \
    /* stage 2 */ \
    "v_mul_f32 v46, v60, v56\n\t" \
    "v_sub_f32 v47, v46, v61\n\t" \
    "v_fma_f32 v53, %0, v56, v61\n\t" \
    "v_pk_fma_f32 v[62:63], v[30:31], v[46:47], v[40:41]\n\t" \
    "v_fma_f32 v57, 0.5, v53, v42\n\t"       /* I3             */ \
    /* stage 3 */ \
    "v_mul_f32 v48, v62, v57\n\t" \
    "v_sub_f32 v49, v48, v63\n\t" \
    "v_fma_f32 v54, %0, v57, v63\n\t" \
    "v_pk_fma_f32 v[64:65], v[32:33], v[48:49], v[40:41]\n\t" \
    "v_add_f32 v58, v54, v42\n\t"            /* I4 = k3 + I    */ \
    /* stage 4 */ \
    "v_mul_f32 v50, v64, v58\n\t" \
    "v_sub_f32 v51, v50, v65\n\t" \
    "v_fma_f32 v55, %0, v58, v65\n\t" \
    /* PQ combine */ \
    "v_pk_fma_f32 v[66:67], v[36:37], v[46:47], v[44:45]\n\t" \
    "v_pk_fma_f32 v[66:67], v[36:37], v[48:49], v[66:67]\n\t" \
    "v_pk_add_f32 v[66:67], v[66:67], v[50:51]\n\t" \
    "v_pk_fma_f32 v[40:41], v[34:35], v[66:67], v[40:41]\n\t" \
    /* I / J(folded wb) combine */ \
    "v_add_f32 v68, v53, v54\n\t"            /* t  = k2+k3     */ \
    "v_add_f32 v69, v52, v68\n\t"            /* sk = k1+t      */ \
    "v_add_f32 v70, v69, v68\n\t"            /* u  = sk+t      */ \
    "v_add_f32 v71, v70, v55\n\t"            /* aI = u+k4      */ \
    "v_fma_f32 v43, %1, v42, v43\n\t"        /* wb += cJ1*I    */ \
    "v_fma_f32 v43, %2, v69, v43\n\t"        /* wb += cJ2*sk   */ \
    "v_fma_f32 v42, %3, v71, v42\n\t"        /* I += aI/6      */ \
    /* output */ \
    "v_fma_f32 v72, %4, v42, v43\n\t" \
    "v_fma_f32 v72, %5, v40, v72\n\t" \
    "v_fma_f32 v72, %6, v41, v72\n\t" \
    "global_store_dword v73, v72, %7\n\t" \
    "v_add_u32 v73, 0x4000, v73\n\t"

__global__ __launch_bounds__(64, 1) void seirm_traj_kernel(
    const float* __restrict__ ze_init,  // [1, B, 5]
    const float* __restrict__ tv,       // [T]
    const float* __restrict__ theta,    // [4] beta, alpha, gamma, mu
    const float* __restrict__ Wv,       // [1, 5]
    const float* __restrict__ bv,       // [1]
    float* __restrict__ out)            // [T, B, 1]
{
    const int b = blockIdx.x * 64 + (int)threadIdx.x;

    const float beta  = theta[0];
    const float alpha = theta[1];
    const float gam   = theta[2];
    const float mu    = theta[3];

    const float w0 = Wv[0], w1 = Wv[1], w2 = Wv[2], w3 = Wv[3], w4 = Wv[4];
    const float bias = bv[0];

    const float h  = tv[1] - tv[0];     // uniform grid
    const float bh = beta * h;
    const float ah = alpha * h;
    const float gh = (gam + mu) * h;
    const float ngh = -gh;              // pre-negated (avoid asm src modifier)
    constexpr float SIXTH = 1.0f / 6.0f;

    const float w0p = w0 / bh;
    const float w1p = w1 / ah;
    const float wJ  = fmaf(w3, gam, w4 * mu);
    const float cJ1 = wJ * h;
    const float cJ2 = wJ * h * SIXTH;

    const float S0 = ze_init[b * 5 + 0];
    const float E0 = ze_init[b * 5 + 1];
    const float I0 = ze_init[b * 5 + 2];
    const float R0 = ze_init[b * 5 + 3];
    const float M0 = ze_init[b * 5 + 4];

    const float p0  = bh * S0;
    const float q0  = ah * E0;
    const float wb0 = fmaf(w3, R0, fmaf(w4, M0, bias));

    // t=0 output
    out[b] = fmaf(w0p, p0, fmaf(w1p, q0, fmaf(w2, I0, wb0)));

    const int voff0 = (b << 2) + BATCH * 4;   // first store -> row 1

    // ---- init fixed registers ----
    asm volatile(
        "v_mov_b32 v40, %0\n\t"
        "v_mov_b32 v41, %1\n\t"
        "v_mov_b32 v42, %2\n\t"
        "v_mov_b32 v43, %3\n\t"
        "v_mov_b32 v73, %4\n\t"
        "v_mov_b32 v30, %5\n\t"
        "v_mov_b32 v31, %6\n\t"
        "v_mov_b32 v32, %7\n\t"
        "v_mov_b32 v33, %8\n\t"
        "v_mov_b32 v34, %9\n\t"
        "v_mov_b32 v35, %10\n\t"
        "v_mov_b32 v36, 2.0\n\t"
        "v_mov_b32 v37, 2.0\n\t"
        :
        : "v"(p0), "v"(q0), "v"(I0), "v"(wb0), "v"(voff0),
          "v"(-0.5f * bh), "v"(0.5f * ah), "v"(-bh), "v"(ah),
          "v"(-bh * SIXTH), "v"(ah * SIXTH)
        : CLOB);

    // ---- 511 = 73 x 7 RK4 steps, R9 34-instr body, loop control amortized ----
    #pragma clang loop unroll(disable)
    for (int i = 0; i < 73; ++i) {
        asm volatile(
            BODY BODY BODY BODY BODY BODY BODY
            :
            : "s"(ngh), "s"(cJ1), "s"(cJ2), "s"(SIXTH),
              "s"(w2), "s"(w0p), "s"(w1p), "s"(out)
            : CLOB);
    }
}

extern "C" void kernel_launch(void* const* d_in, const int* in_sizes, int n_in,
                              void* d_out, int out_size, void* d_ws, size_t ws_size,
                              hipStream_t stream) {
    const float* ze = (const float*)d_in[0];
    const float* tv = (const float*)d_in[1];
    const float* th = (const float*)d_in[2];
    const float* Wv = (const float*)d_in[3];
    const float* bv = (const float*)d_in[4];
    float* out = (float*)d_out;

    seirm_traj_kernel<<<BATCH / 64, 64, 0, stream>>>(ze, tv, th, Wv, bv, out);
}